// Round 16
// baseline (199.834 us; speedup 1.0000x reference)
//
#include <hip/hip_runtime.h>
#include <hip/hip_bf16.h>

// Shapes: EMBED=HIDDEN=512, VOCAB=30000, B=16, S=128, K=49, NT=5, rows BS=2048

typedef short bf16x8 __attribute__((ext_vector_type(8)));
typedef float f32x4 __attribute__((ext_vector_type(4)));
typedef short short8 __attribute__((ext_vector_type(8)));

static __device__ __forceinline__ short f2bf(float f) {
    union { float f; unsigned u; } v; v.f = f;
    unsigned r = v.u + 0x7FFFu + ((v.u >> 16) & 1u);   // RNE
    return (short)(r >> 16);
}

static __device__ __forceinline__ void cvt_blk(const float* __restrict__ src,
                                               short* __restrict__ dst, int i) {
    const float4 a = ((const float4*)src)[i * 2];
    const float4 b = ((const float4*)src)[i * 2 + 1];
    short8 o;
    o[0] = f2bf(a.x); o[1] = f2bf(a.y); o[2] = f2bf(a.z); o[3] = f2bf(a.w);
    o[4] = f2bf(b.x); o[5] = f2bf(b.y); o[6] = f2bf(b.z); o[7] = f2bf(b.w);
    ((short8*)dst)[i] = o;
}

#define GLD_LDS16(gp, lp)                                                          \
    __builtin_amdgcn_global_load_lds(                                              \
        (const __attribute__((address_space(1))) unsigned int*)(gp),               \
        (__attribute__((address_space(3))) unsigned int*)(lp), 16, 0, 0)

// ---------------------------------------------------------------------------
// K_front: only conversions the k_linhv stage needs (critical path).
__global__ __launch_bounds__(256) void k_front(
    const float* __restrict__ h, const float* __restrict__ V, const float* __restrict__ T,
    const float* __restrict__ W_Zh, const float* __restrict__ W_Qh,
    const float* __restrict__ W_ZV, const float* __restrict__ W_QT,
    short* __restrict__ P1, short* __restrict__ P2, short* __restrict__ P3,
    short* __restrict__ V_b, short* __restrict__ T_b, short* __restrict__ h_b)
{
    const int bid = blockIdx.x;
    const int t = threadIdx.x;

    if (bid < 48) {                           // weight packs
        const int pid = bid >> 4, blk = bid & 15;
        short* dst = (pid == 0) ? P1 : (pid == 1) ? P2 : P3;
        const int base = blk * 2048 + t * 8;  // 8 elems, same 512-col row
        const int r = base >> 9, c = base & 511;
        const float* srow = nullptr;
        if (pid == 0)      srow = (r < 49) ? (W_Zh + r * 512) : ((r < 54) ? (W_Qh + (r - 49) * 512) : nullptr);
        else if (pid == 1) srow = (r < 49) ? (W_ZV + r * 512) : nullptr;
        else               srow = (r < 5)  ? (W_QT + r * 512) : nullptr;
        short8 o = {0, 0, 0, 0, 0, 0, 0, 0};
        if (srow) {
            const float4 a = *(const float4*)(srow + c);
            const float4 b = *(const float4*)(srow + c + 4);
            o[0] = f2bf(a.x); o[1] = f2bf(a.y); o[2] = f2bf(a.z); o[3] = f2bf(a.w);
            o[4] = f2bf(b.x); o[5] = f2bf(b.y); o[6] = f2bf(b.z); o[7] = f2bf(b.w);
        }
        *(short8*)(dst + base) = o;
        return;
    }
    if (bid < 244)      cvt_blk(V, V_b, (bid - 48) * 256 + t);
    else if (bid < 264) cvt_blk(T, T_b, (bid - 244) * 256 + t);
    else                cvt_blk(h, h_b, (bid - 264) * 256 + t);
}

// ---------------------------------------------------------------------------
// K_linhv: MFMA linears for the attention fronts (64x64 tile).
__global__ __launch_bounds__(256) void k_linhv(
    const short* __restrict__ h_b, const short* __restrict__ V_b, const short* __restrict__ T_b,
    const short* __restrict__ P1, const short* __restrict__ P2, const short* __restrict__ P3,
    const float* __restrict__ b_Zh, const float* __restrict__ b_Qh,
    const float* __restrict__ b_ZV, const float* __restrict__ b_QT,
    float* __restrict__ Zh, float* __restrict__ Qh,
    float* __restrict__ ZV, float* __restrict__ QT)
{
    constexpr int K = 512;
    const int bid = blockIdx.x;
    int sect, m0;
    const short *Ag, *Wg;
    if (bid < 32)      { sect = 0; m0 = bid * 64;        Ag = h_b; Wg = P1; }
    else if (bid < 45) { sect = 1; m0 = (bid - 32) * 64; Ag = V_b; Wg = P2; }
    else               { sect = 2; m0 = (bid - 45) * 64; Ag = T_b; Wg = P3; }

    __shared__ __align__(16) short sA[64 * 64];
    __shared__ __align__(16) short sW[64 * 64];
    const int tid = threadIdx.x;
    const int l = tid & 63, w = tid >> 6;
    const int wm = (w & 1) * 32, wn = (w >> 1) * 32;
    const int lm = l & 15, lg = l >> 4;
    const int sr = l >> 3, sc = l & 7;
    f32x4 acc[2][2] = {};

    for (int k0 = 0; k0 < K; k0 += 64) {
        #pragma unroll
        for (int c = 0; c < 2; ++c) {
            const int R = w * 16 + c * 8;
            const int row = R + sr;
            GLD_LDS16(Ag + (size_t)(m0 + row) * K + k0 + ((sc ^ (row & 7)) << 3), sA + R * 64);
            GLD_LDS16(Wg + (size_t)row * K + k0 + ((sc ^ (row & 7)) << 3), sW + R * 64);
        }
        __syncthreads();
        bf16x8 af[2][2], bv[2][2];
        #pragma unroll
        for (int s = 0; s < 2; ++s)
            #pragma unroll
            for (int i = 0; i < 2; ++i) {
                const int ra = wm + i * 16 + lm;
                const int rb = wn + i * 16 + lm;
                af[s][i] = *(const bf16x8*)(sA + ra * 64 + (((s * 4 + lg) ^ (ra & 7)) << 3));
                bv[s][i] = *(const bf16x8*)(sW + rb * 64 + (((s * 4 + lg) ^ (rb & 7)) << 3));
            }
        #pragma unroll
        for (int s = 0; s < 2; ++s)
            #pragma unroll
            for (int i = 0; i < 2; ++i)
                #pragma unroll
                for (int j = 0; j < 2; ++j)
                    acc[i][j] = __builtin_amdgcn_mfma_f32_16x16x32_bf16(af[s][i], bv[s][j], acc[i][j], 0, 0, 0);
        __syncthreads();
    }

    #pragma unroll
    for (int j = 0; j < 2; ++j) {
        const int n = wn + j * 16 + lm;        // 0..63 output col
        #pragma unroll
        for (int i = 0; i < 2; ++i) {
            #pragma unroll
            for (int q = 0; q < 4; ++q) {
                const int m = m0 + wm + i * 16 + lg * 4 + q;
                const float v = acc[i][j][q];
                if (sect == 0) {
                    if (n < 49)      Zh[(size_t)m * 64 + n] = v + b_Zh[n];
                    else if (n < 54) Qh[(size_t)m * 8 + (n - 49)] = v + b_Qh[n - 49];
                } else if (sect == 1) {
                    if (m < 784 && n < 49) ZV[(size_t)m * 64 + n] = v + b_ZV[n];
                } else {
                    if (m < 80 && n < 5) QT[(size_t)m * 8 + n] = v + b_QT[n];
                }
            }
        }
    }
}

// ---------------------------------------------------------------------------
// K3: blocks [0,2048): per (b,s) visual+topic attention -> z_bf, q_bf.
//     blocks [2048,9932): trailing fp32->bf16 conversions.
__global__ void k_attn(const float* __restrict__ V, const float* __restrict__ T,
                       const float* __restrict__ ZV, const float* __restrict__ Zh,
                       const float* __restrict__ QT, const float* __restrict__ Qh,
                       const float* __restrict__ W_az, const float* __restrict__ b_az,
                       const float* __restrict__ W_bq, const float* __restrict__ b_bq,
                       short* __restrict__ z_bf, short* __restrict__ q_bf,
                       const float* __restrict__ wsz, short* __restrict__ wsz_b,
                       const float* __restrict__ wsq, short* __restrict__ wsq_b,
                       const float* __restrict__ wsh, short* __restrict__ wsh_b,
                       const float* __restrict__ wmlp, short* __restrict__ wmlp_b)
{
    const int bid = blockIdx.x;
    const int t = threadIdx.x;
    if (bid >= 2048) {                    // conversion tail
        if (bid < 2176)      cvt_blk(wsz, wsz_b, (bid - 2048) * 256 + t);
        else if (bid < 2304) cvt_blk(wsq, wsq_b, (bid - 2176) * 256 + t);
        else if (bid < 2432) cvt_blk(wsh, wsh_b, (bid - 2304) * 256 + t);
        else                 cvt_blk(wmlp, wmlp_b, (bid - 2432) * 256 + t);
        return;
    }
    const int row = bid;                  // b*128+s
    const int b = row >> 7;
    __shared__ float zh[49], waz[49], alpha[49], beta[5];
    if (t < 49) { zh[t] = Zh[row * 64 + t]; waz[t] = W_az[t]; }
    __syncthreads();
    if (t < 49) {
        const float* zv = ZV + (b * 49 + t) * 64;
        float acc = b_az[0];
        for (int j = 0; j < 49; ++j) acc += tanhf(zv[j] + zh[j]) * waz[j];
        alpha[t] = acc;
    } else if (t >= 64 && t < 69) {
        const int tt = t - 64;
        const float* qt = QT + (b * 5 + tt) * 8;
        const float* qh = Qh + row * 8;
        float acc = b_bq[0];
        for (int j = 0; j < 5; ++j) acc += tanhf(qt[j] + qh[j]) * W_bq[j];
        beta[tt] = acc;
    }
    __syncthreads();
    const int wv = t >> 6, l = t & 63;
    if (wv == 0) {
        float a = (l < 49) ? alpha[l] : -1e30f;
        float m = a;
        #pragma unroll
        for (int off = 32; off; off >>= 1) m = fmaxf(m, __shfl_xor(m, off));
        float e = (l < 49) ? expf(a - m) : 0.f;
        float s = e;
        #pragma unroll
        for (int off = 32; off; off >>= 1) s += __shfl_xor(s, off);
        if (l < 49) alpha[l] = e / s;
    } else if (wv == 1) {
        float a = (l < 5) ? beta[l] : -1e30f;
        float m = a;
        #pragma unroll
        for (int off = 32; off; off >>= 1) m = fmaxf(m, __shfl_xor(m, off));
        float e = (l < 5) ? expf(a - m) : 0.f;
        float s = e;
        #pragma unroll
        for (int off = 32; off; off >>= 1) s += __shfl_xor(s, off);
        if (l < 5) beta[l] = e / s;
    }
    __syncthreads();
    const float* Vb = V + (size_t)b * 49 * 512;
    const float* Tb = T + (size_t)b * 5 * 512;
    for (int hd = t; hd < 512; hd += 256) {
        float az = 0.f;
        #pragma unroll
        for (int k = 0; k < 49; ++k) az = fmaf(alpha[k], Vb[k * 512 + hd], az);
        z_bf[(size_t)row * 512 + hd] = f2bf(az);
        float aq = 0.f;
        #pragma unroll
        for (int k = 0; k < 5; ++k) aq = fmaf(beta[k], Tb[k * 512 + hd], aq);
        q_bf[(size_t)row * 512 + hd] = f2bf(aq);
    }
}

// ---------------------------------------------------------------------------
// K4: r_t = tanh(z@Wsz.T + b_sz), s_t = tanh(q@Wsq.T + h@Wsh.T + b_sq + b_sh)
__global__ __launch_bounds__(256) void k_rs(
    const short* __restrict__ Zb, const short* __restrict__ Qb, const short* __restrict__ Hb,
    const short* __restrict__ Wsz, const short* __restrict__ Wsq, const short* __restrict__ Wsh,
    const float* __restrict__ b_sz, const float* __restrict__ b_sq, const float* __restrict__ b_sh,
    float* __restrict__ r_t, float* __restrict__ s_t)
{
    constexpr int K = 512, NN = 512;
    __shared__ __align__(16) short sA[64 * 64];
    __shared__ __align__(16) short sW[64 * 64];
    const int tid = threadIdx.x;
    const int l = tid & 63, w = tid >> 6;
    const int m0 = blockIdx.x * 64, n0 = blockIdx.y * 64;
    const int wm = (w & 1) * 32, wn = (w >> 1) * 32;
    const int lm = l & 15, lg = l >> 4;
    const int sr = l >> 3, sc = l & 7;
    f32x4 accr[2][2] = {}, accs[2][2] = {};

#define RS_PASS(AG, WG, ACC)                                                      \
    for (int k0 = 0; k0 < K; k0 += 64) {                                          \
        _Pragma("unroll")                                                         \
        for (int c = 0; c < 2; ++c) {                                             \
            const int R = w * 16 + c * 8;                                         \
            const int row = R + sr;                                               \
            GLD_LDS16((AG) + (size_t)(m0 + row) * K + k0 + ((sc ^ (row & 7)) << 3), sA + R * 64); \
            GLD_LDS16((WG) + (size_t)(n0 + row) * K + k0 + ((sc ^ (row & 7)) << 3), sW + R * 64); \
        }                                                                         \
        __syncthreads();                                                          \
        bf16x8 af[2][2], bv[2][2];                                                \
        _Pragma("unroll")                                                         \
        for (int s = 0; s < 2; ++s)                                               \
            _Pragma("unroll")                                                     \
            for (int i = 0; i < 2; ++i) {                                         \
                const int ra = wm + i * 16 + lm;                                  \
                const int rb = wn + i * 16 + lm;                                  \
                af[s][i] = *(const bf16x8*)(sA + ra * 64 + (((s * 4 + lg) ^ (ra & 7)) << 3)); \
                bv[s][i] = *(const bf16x8*)(sW + rb * 64 + (((s * 4 + lg) ^ (rb & 7)) << 3)); \
            }                                                                     \
        _Pragma("unroll")                                                         \
        for (int s = 0; s < 2; ++s)                                               \
            _Pragma("unroll")                                                     \
            for (int i = 0; i < 2; ++i)                                           \
                _Pragma("unroll")                                                 \
                for (int j = 0; j < 2; ++j)                                       \
                    ACC[i][j] = __builtin_amdgcn_mfma_f32_16x16x32_bf16(af[s][i], bv[s][j], ACC[i][j], 0, 0, 0); \
        __syncthreads();                                                          \
    }

    RS_PASS(Zb, Wsz, accr)
    RS_PASS(Qb, Wsq, accs)
    RS_PASS(Hb, Wsh, accs)
#undef RS_PASS

    #pragma unroll
    for (int j = 0; j < 2; ++j) {
        const int n = n0 + wn + j * 16 + lm;
        const float br = b_sz[n];
        const float bs = b_sq[n] + b_sh[n];
        #pragma unroll
        for (int i = 0; i < 2; ++i) {
            const int m = m0 + wm + i * 16 + lg * 4;
            #pragma unroll
            for (int q = 0; q < 4; ++q) {
                r_t[(size_t)(m + q) * NN + n] = tanhf(accr[i][j][q] + br);
                s_t[(size_t)(m + q) * NN + n] = tanhf(accs[i][j][q] + bs);
            }
        }
    }
}

// ---------------------------------------------------------------------------
// K7: gate + blend -> c_bf in MFMA-fragment-TILED layout.
// Tile (tm=m>>7, tk=k>>6) of 8192 elems; fragment frag = half*8 + i*2 + s
// (half=(m>>6)&1, i=(m>>4)&3, s=(k&63)>>5) of 512 elems at frag*512;
// within fragment: lg*128 + lm*8 + e  (lg=(k>>3)&3, lm=m&15, e=k&7).
__global__ __launch_bounds__(256) void k_blend_gate(
    const float* __restrict__ s_t, const float* __restrict__ r_t,
    const float* __restrict__ Qh,
    const float* __restrict__ W_Ss, const float* __restrict__ b_Ss,
    const float* __restrict__ W_Sr, const float* __restrict__ b_Sr,
    const float* __restrict__ W_bq, const float* __restrict__ b_bq,
    const int* __restrict__ epoch, short* __restrict__ c_bf)
{
    const int row = blockIdx.x * 4 + (threadIdx.x >> 6);
    const int l = threadIdx.x & 63;
    float g = 1.0f;
    if (epoch[0] > 20) {
        const int sg = row & 127;            // gate row (batch 0, diagonal)
        const int d = l * 8;
        const float4 s0 = *(const float4*)(s_t + (size_t)sg * 512 + d);
        const float4 s1 = *(const float4*)(s_t + (size_t)sg * 512 + d + 4);
        const float4 r0 = *(const float4*)(r_t + (size_t)sg * 512 + d);
        const float4 r1 = *(const float4*)(r_t + (size_t)sg * 512 + d + 4);
        float ss = b_bq[0], sr = b_bq[0];
        #pragma unroll
        for (int k = 0; k < 5; ++k) {
            const float4 w0 = *(const float4*)(W_Ss + k * 512 + d);
            const float4 w1 = *(const float4*)(W_Ss + k * 512 + d + 4);
            const float4 v0 = *(const float4*)(W_Sr + k * 512 + d);
            const float4 v1 = *(const float4*)(W_Sr + k * 512 + d + 4);
            float as = s0.x*w0.x + s0.y*w0.y + s0.z*w0.z + s0.w*w0.w
                     + s1.x*w1.x + s1.y*w1.y + s1.z*w1.z + s1.w*w1.w;
            float ar = r0.x*v0.x + r0.y*v0.y + r0.z*v0.z + r0.w*v0.w
                     + r1.x*v1.x + r1.y*v1.y + r1.z*v1.z + r1.w*v1.w;
            #pragma unroll
            for (int off = 32; off; off >>= 1) {
                as += __shfl_xor(as, off);
                ar += __shfl_xor(ar, off);
            }
            const float qh = Qh[sg * 8 + k];
            ss += tanhf(as + b_Ss[k] + qh) * W_bq[k];
            sr += tanhf(ar + b_Sr[k] + qh) * W_bq[k];
        }
        g = 1.f / (1.f + expf(-(ss - sr)));
    }
    // blend chunk l (k = 8l..8l+7) of this row, write tiled
    const int kk = l * 8;
    const float4 a0 = *(const float4*)(s_t + (size_t)row * 512 + kk);
    const float4 a1 = *(const float4*)(s_t + (size_t)row * 512 + kk + 4);
    const float4 b0 = *(const float4*)(r_t + (size_t)row * 512 + kk);
    const float4 b1 = *(const float4*)(r_t + (size_t)row * 512 + kk + 4);
    short8 o;
    o[0] = f2bf(g * a0.x + (1.f - g) * b0.x);
    o[1] = f2bf(g * a0.y + (1.f - g) * b0.y);
    o[2] = f2bf(g * a0.z + (1.f - g) * b0.z);
    o[3] = f2bf(g * a0.w + (1.f - g) * b0.w);
    o[4] = f2bf(g * a1.x + (1.f - g) * b1.x);
    o[5] = f2bf(g * a1.y + (1.f - g) * b1.y);
    o[6] = f2bf(g * a1.z + (1.f - g) * b1.z);
    o[7] = f2bf(g * a1.w + (1.f - g) * b1.w);
    const int tm = row >> 7, rm = row & 127;
    const int half = (rm >> 6) & 1, i2 = (rm >> 4) & 3, lm = rm & 15;
    const int tk = l >> 3, cc = l & 7, s2 = cc >> 2, lg = cc & 3;
    const int frag = half * 8 + i2 * 2 + s2;          // 0..15, 512 elems each
    const size_t off = ((size_t)(tm * 8 + tk)) * 8192
                     + (size_t)(frag * 512 + lg * 128 + lm * 8);
    *(short8*)(c_bf + off) = o;
}

// ---------------------------------------------------------------------------
// K5: MLP GEMM: 128x128 tile, W via LDS (16 KB single-buffer), A read DIRECTLY
// from the fragment-tiled c_bf (coalesced 1KB wave fragment loads, L2-resident)
// — halves the barrier-drained staging volume. T1 XCD swizzle, nt stores.
__global__ __launch_bounds__(256, 4) void k_gemm_mlp(
    const short* __restrict__ At, const short* __restrict__ Wb,
    const float* __restrict__ bias, float* __restrict__ C)
{
    constexpr int N = 30000, K = 512;
    __shared__ __align__(16) short shW[128 * 64];      // 16 KB
    const int tid = threadIdx.x;
    const int l = tid & 63, w = tid >> 6;
    const int bid = blockIdx.x;
    const int swz = (bid & 7) * 470 + (bid >> 3);      // bijective (3760%8==0)
    const int m0 = (swz & 15) * 128;                   // m fast -> W panel reuse
    const int n0 = (swz >> 4) * 128;
    const int wm = (w & 1) * 64, wn = (w >> 1) * 64;
    const int lm = l & 15, lg = l >> 4;
    const int sr = tid >> 3, sc = tid & 7;             // staging row(32/call), chunk
    const short* Wg = Wb + (size_t)n0 * K;
    // A tiled base: tile row (swz&15), half = w&1 -> frag base half*8*512
    const short* Ab = At + (size_t)(swz & 15) * 8 * 8192 + (size_t)(w & 1) * 8 * 512 + l * 8;
    f32x4 acc[4][4] = {};

    for (int t = 0; t < 8; ++t) {
        const int kk = t * 64;
        #pragma unroll
        for (int c = 0; c < 4; ++c) {
            const int row = c * 32 + sr;
            GLD_LDS16(Wg + (size_t)row * K + kk + ((sc ^ (row & 7)) << 3),
                      &shW[(c * 32 + w * 8) * 64]);
        }
        // A fragments direct from L2: frag = i*2 + s (within half), 512 elems
        bf16x8 af[2][4];
        const short* Abt = Ab + (size_t)t * 8192;
        #pragma unroll
        for (int i = 0; i < 4; ++i) {
            af[0][i] = *(const bf16x8*)(Abt + (i * 2 + 0) * 512);
            af[1][i] = *(const bf16x8*)(Abt + (i * 2 + 1) * 512);
        }
        __syncthreads();                               // drains vmcnt (W in LDS)
        bf16x8 bv[2][4];
        #pragma unroll
        for (int s = 0; s < 2; ++s)
            #pragma unroll
            for (int i = 0; i < 4; ++i) {
                const int rb = wn + i * 16 + lm;
                bv[s][i] = *(const bf16x8*)(&shW[rb * 64 + (((s * 4 + lg) ^ (rb & 7)) << 3)]);
            }
        #pragma unroll
        for (int s = 0; s < 2; ++s)
            #pragma unroll
            for (int i = 0; i < 4; ++i)
                #pragma unroll
                for (int j = 0; j < 4; ++j)
                    acc[i][j] = __builtin_amdgcn_mfma_f32_16x16x32_bf16(
                        af[s][i], bv[s][j], acc[i][j], 0, 0, 0);
        __syncthreads();                               // LDS free for next stage
    }

    // epilogue: C/D layout col = l&15, row = (l>>4)*4 + reg; nt scalar stores
    #pragma unroll
    for (int j = 0; j < 4; ++j) {
        const int n = n0 + wn + j * 16 + lm;
        if (n >= N) continue;
        const float bj = bias[n];
        #pragma unroll
        for (int i = 0; i < 4; ++i) {
            const int m = m0 + wm + i * 16 + lg * 4;
            #pragma unroll
            for (int q = 0; q < 4; ++q)
                __builtin_nontemporal_store(acc[i][j][q] + bj, &C[(size_t)(m + q) * N + n]);
        }
    }
}

// ---------------------------------------------------------------------------
extern "C" void kernel_launch(void* const* d_in, const int* in_sizes, int n_in,
                              void* d_out, int out_size, void* d_ws, size_t ws_size,
                              hipStream_t stream)
{
    const int*   epoch = (const int*)  d_in[0];
    const float* h_t   = (const float*)d_in[1];
    const float* V     = (const float*)d_in[2];
    const float* T     = (const float*)d_in[3];
    const float* W_ZV  = (const float*)d_in[4];  const float* b_ZV = (const float*)d_in[5];
    const float* W_Zh  = (const float*)d_in[6];  const float* b_Zh = (const float*)d_in[7];
    const float* W_az  = (const float*)d_in[8];  const float* b_az = (const float*)d_in[9];
    const float* W_QT  = (const float*)d_in[10]; const float* b_QT = (const float*)d_in[11];
    const float* W_Qh  = (const float*)d_in[12]; const float* b_Qh = (const float*)d_in[13];
    const float* W_bq  = (const float*)d_in[14]; const float* b_bq = (const float*)d_in[15];
    const float* W_sq  = (const float*)d_in[16]; const float* b_sq = (const float*)d_in[17];
    const float* W_sh  = (const float*)d_in[18]; const float* b_sh = (const float*)d_in[19];
    const float* W_Ss  = (const float*)d_in[20]; const float* b_Ss = (const float*)d_in[21];
    const float* W_Sr  = (const float*)d_in[22]; const float* b_Sr = (const float*)d_in[23];
    const float* W_sz  = (const float*)d_in[24]; const float* b_sz = (const float*)d_in[25];
    const float* W_mlp = (const float*)d_in[26]; const float* b_mlp= (const float*)d_in[27];

    float* out = (float*)d_out;
    float* ws  = (float*)d_ws;
    const size_t M1 = 1024 * 1024;        // 2048*512
    float* r_t  = ws;                     // 1M f
    float* s_t  = ws + M1;                // 1M f
    float* Zh   = ws + 2 * M1;            // 2048*64 f
    float* ZV   = Zh + 2048 * 64;         // 784*64 f
    float* Qh   = ZV + 784 * 64;          // 2048*8 f
    float* QT   = Qh + 2048 * 8;          // 80*8 f
    float* pad  = QT + 80 * 8;            // 128 f
    short* sreg = (short*)(pad + 128);
    short* z_bf   = sreg;                 // 1M sh
    short* q_bf   = z_bf + M1;            // 1M sh
    short* h_bf   = q_bf + M1;            // 1M sh
    short* c_bf   = h_bf + M1;            // 1M sh (fragment-tiled layout)
    short* Wsz_bf = c_bf + M1;            // 256K sh
    short* Wsq_bf = Wsz_bf + 512 * 512;
    short* Wsh_bf = Wsq_bf + 512 * 512;
    short* V_bf   = Wsh_bf + 512 * 512;   // 832*512 sh (784 real + pad)
    short* T_bf   = V_bf + 832 * 512;     // 128*512 sh (80 real + pad)
    short* P1     = T_bf + 128 * 512;     // 64*512 sh
    short* P2     = P1 + 64 * 512;
    short* P3     = P2 + 64 * 512;
    short* W_bf   = P3 + 64 * 512;        // 30080*512 sh (incl. pad)

    k_front<<<776, 256, 0, stream>>>(h_t, V, T, W_Zh, W_Qh, W_ZV, W_QT,
                                     P1, P2, P3, V_bf, T_bf, h_bf);
    k_linhv<<<47, 256, 0, stream>>>(h_bf, V_bf, T_bf, P1, P2, P3,
                                    b_Zh, b_Qh, b_ZV, b_QT, Zh, Qh, ZV, QT);
    k_attn<<<9932, 256, 0, stream>>>(V, T, ZV, Zh, QT, Qh, W_az, b_az, W_bq, b_bq,
                                     z_bf, q_bf,
                                     W_sz, Wsz_bf, W_sq, Wsq_bf, W_sh, Wsh_bf,
                                     W_mlp, W_bf);
    k_rs<<<dim3(32, 8), 256, 0, stream>>>(z_bf, q_bf, h_bf, Wsz_bf, Wsq_bf, Wsh_bf,
                                          b_sz, b_sq, b_sh, r_t, s_t);
    k_blend_gate<<<512, 256, 0, stream>>>(s_t, r_t, Qh, W_Ss, b_Ss, W_Sr, b_Sr,
                                          W_bq, b_bq, epoch, c_bf);
    k_gemm_mlp<<<3760, 256, 0, stream>>>(c_bf, W_bf, b_mlp, out);
}

// Round 17
// 176.318 us; speedup vs baseline: 1.1334x; 1.1334x over previous
//
#include <hip/hip_runtime.h>
#include <hip/hip_bf16.h>

// Shapes: EMBED=HIDDEN=512, VOCAB=30000, B=16, S=128, K=49, NT=5, rows BS=2048

typedef short bf16x8 __attribute__((ext_vector_type(8)));
typedef float f32x4 __attribute__((ext_vector_type(4)));
typedef short short8 __attribute__((ext_vector_type(8)));

static __device__ __forceinline__ short f2bf(float f) {
    union { float f; unsigned u; } v; v.f = f;
    unsigned r = v.u + 0x7FFFu + ((v.u >> 16) & 1u);   // RNE
    return (short)(r >> 16);
}

static __device__ __forceinline__ void cvt_blk(const float* __restrict__ src,
                                               short* __restrict__ dst, int i) {
    const float4 a = ((const float4*)src)[i * 2];
    const float4 b = ((const float4*)src)[i * 2 + 1];
    short8 o;
    o[0] = f2bf(a.x); o[1] = f2bf(a.y); o[2] = f2bf(a.z); o[3] = f2bf(a.w);
    o[4] = f2bf(b.x); o[5] = f2bf(b.y); o[6] = f2bf(b.z); o[7] = f2bf(b.w);
    ((short8*)dst)[i] = o;
}

#define GLD_LDS16(gp, lp)                                                          \
    __builtin_amdgcn_global_load_lds(                                              \
        (const __attribute__((address_space(1))) unsigned int*)(gp),               \
        (__attribute__((address_space(3))) unsigned int*)(lp), 16, 0, 0)

// ---------------------------------------------------------------------------
// K_front: pure fp32->bf16 conversion + weight packing, critical path first.
__global__ __launch_bounds__(256) void k_front(
    const float* __restrict__ h, const float* __restrict__ V, const float* __restrict__ T,
    const float* __restrict__ W_Zh, const float* __restrict__ W_Qh,
    const float* __restrict__ W_ZV, const float* __restrict__ W_QT,
    short* __restrict__ P1, short* __restrict__ P2, short* __restrict__ P3,
    short* __restrict__ V_b, short* __restrict__ T_b, short* __restrict__ h_b,
    const float* __restrict__ wsz, short* __restrict__ wsz_b,
    const float* __restrict__ wsq, short* __restrict__ wsq_b,
    const float* __restrict__ wsh, short* __restrict__ wsh_b,
    const float* __restrict__ wmlp, short* __restrict__ wmlp_b)
{
    const int bid = blockIdx.x;
    const int t = threadIdx.x;

    if (bid < 48) {                           // weight packs
        const int pid = bid >> 4, blk = bid & 15;
        short* dst = (pid == 0) ? P1 : (pid == 1) ? P2 : P3;
        const int base = blk * 2048 + t * 8;  // 8 elems, same 512-col row
        const int r = base >> 9, c = base & 511;
        const float* srow = nullptr;
        if (pid == 0)      srow = (r < 49) ? (W_Zh + r * 512) : ((r < 54) ? (W_Qh + (r - 49) * 512) : nullptr);
        else if (pid == 1) srow = (r < 49) ? (W_ZV + r * 512) : nullptr;
        else               srow = (r < 5)  ? (W_QT + r * 512) : nullptr;
        short8 o = {0, 0, 0, 0, 0, 0, 0, 0};
        if (srow) {
            const float4 a = *(const float4*)(srow + c);
            const float4 b = *(const float4*)(srow + c + 4);
            o[0] = f2bf(a.x); o[1] = f2bf(a.y); o[2] = f2bf(a.z); o[3] = f2bf(a.w);
            o[4] = f2bf(b.x); o[5] = f2bf(b.y); o[6] = f2bf(b.z); o[7] = f2bf(b.w);
        }
        *(short8*)(dst + base) = o;
        return;
    }
    if (bid < 244)       cvt_blk(V, V_b, (bid - 48) * 256 + t);
    else if (bid < 264)  cvt_blk(T, T_b, (bid - 244) * 256 + t);
    else if (bid < 776)  cvt_blk(h, h_b, (bid - 264) * 256 + t);
    else if (bid < 904)  cvt_blk(wsz, wsz_b, (bid - 776) * 256 + t);
    else if (bid < 1032) cvt_blk(wsq, wsq_b, (bid - 904) * 256 + t);
    else if (bid < 1160) cvt_blk(wsh, wsh_b, (bid - 1032) * 256 + t);
    else                 cvt_blk(wmlp, wmlp_b, (bid - 1160) * 256 + t);
}

// ---------------------------------------------------------------------------
// K_linhv: MFMA linears for the attention fronts (64x64 tile).
__global__ __launch_bounds__(256) void k_linhv(
    const short* __restrict__ h_b, const short* __restrict__ V_b, const short* __restrict__ T_b,
    const short* __restrict__ P1, const short* __restrict__ P2, const short* __restrict__ P3,
    const float* __restrict__ b_Zh, const float* __restrict__ b_Qh,
    const float* __restrict__ b_ZV, const float* __restrict__ b_QT,
    float* __restrict__ Zh, float* __restrict__ Qh,
    float* __restrict__ ZV, float* __restrict__ QT)
{
    constexpr int K = 512;
    const int bid = blockIdx.x;
    int sect, m0;
    const short *Ag, *Wg;
    if (bid < 32)      { sect = 0; m0 = bid * 64;        Ag = h_b; Wg = P1; }
    else if (bid < 45) { sect = 1; m0 = (bid - 32) * 64; Ag = V_b; Wg = P2; }
    else               { sect = 2; m0 = (bid - 45) * 64; Ag = T_b; Wg = P3; }

    __shared__ __align__(16) short sA[64 * 64];
    __shared__ __align__(16) short sW[64 * 64];
    const int tid = threadIdx.x;
    const int l = tid & 63, w = tid >> 6;
    const int wm = (w & 1) * 32, wn = (w >> 1) * 32;
    const int lm = l & 15, lg = l >> 4;
    const int sr = l >> 3, sc = l & 7;
    f32x4 acc[2][2] = {};

    for (int k0 = 0; k0 < K; k0 += 64) {
        #pragma unroll
        for (int c = 0; c < 2; ++c) {
            const int R = w * 16 + c * 8;
            const int row = R + sr;
            GLD_LDS16(Ag + (size_t)(m0 + row) * K + k0 + ((sc ^ (row & 7)) << 3), sA + R * 64);
            GLD_LDS16(Wg + (size_t)row * K + k0 + ((sc ^ (row & 7)) << 3), sW + R * 64);
        }
        __syncthreads();
        bf16x8 af[2][2], bv[2][2];
        #pragma unroll
        for (int s = 0; s < 2; ++s)
            #pragma unroll
            for (int i = 0; i < 2; ++i) {
                const int ra = wm + i * 16 + lm;
                const int rb = wn + i * 16 + lm;
                af[s][i] = *(const bf16x8*)(sA + ra * 64 + (((s * 4 + lg) ^ (ra & 7)) << 3));
                bv[s][i] = *(const bf16x8*)(sW + rb * 64 + (((s * 4 + lg) ^ (rb & 7)) << 3));
            }
        #pragma unroll
        for (int s = 0; s < 2; ++s)
            #pragma unroll
            for (int i = 0; i < 2; ++i)
                #pragma unroll
                for (int j = 0; j < 2; ++j)
                    acc[i][j] = __builtin_amdgcn_mfma_f32_16x16x32_bf16(af[s][i], bv[s][j], acc[i][j], 0, 0, 0);
        __syncthreads();
    }

    #pragma unroll
    for (int j = 0; j < 2; ++j) {
        const int n = wn + j * 16 + lm;        // 0..63 output col
        #pragma unroll
        for (int i = 0; i < 2; ++i) {
            #pragma unroll
            for (int q = 0; q < 4; ++q) {
                const int m = m0 + wm + i * 16 + lg * 4 + q;
                const float v = acc[i][j][q];
                if (sect == 0) {
                    if (n < 49)      Zh[(size_t)m * 64 + n] = v + b_Zh[n];
                    else if (n < 54) Qh[(size_t)m * 8 + (n - 49)] = v + b_Qh[n - 49];
                } else if (sect == 1) {
                    if (m < 784 && n < 49) ZV[(size_t)m * 64 + n] = v + b_ZV[n];
                } else {
                    if (m < 80 && n < 5) QT[(size_t)m * 8 + n] = v + b_QT[n];
                }
            }
        }
    }
}

// ---------------------------------------------------------------------------
// K3: per (b,s): visual + topic attention -> z_bf, q_bf (2048,512) bf16
__global__ void k_attn(const float* __restrict__ V, const float* __restrict__ T,
                       const float* __restrict__ ZV, const float* __restrict__ Zh,
                       const float* __restrict__ QT, const float* __restrict__ Qh,
                       const float* __restrict__ W_az, const float* __restrict__ b_az,
                       const float* __restrict__ W_bq, const float* __restrict__ b_bq,
                       short* __restrict__ z_bf, short* __restrict__ q_bf)
{
    const int row = blockIdx.x;       // b*128+s
    const int b = row >> 7;
    const int t = threadIdx.x;
    __shared__ float zh[49], waz[49], alpha[49], beta[5];
    if (t < 49) { zh[t] = Zh[row * 64 + t]; waz[t] = W_az[t]; }
    __syncthreads();
    if (t < 49) {
        const float* zv = ZV + (b * 49 + t) * 64;
        float acc = b_az[0];
        for (int j = 0; j < 49; ++j) acc += tanhf(zv[j] + zh[j]) * waz[j];
        alpha[t] = acc;
    } else if (t >= 64 && t < 69) {
        const int tt = t - 64;
        const float* qt = QT + (b * 5 + tt) * 8;
        const float* qh = Qh + row * 8;
        float acc = b_bq[0];
        for (int j = 0; j < 5; ++j) acc += tanhf(qt[j] + qh[j]) * W_bq[j];
        beta[tt] = acc;
    }
    __syncthreads();
    const int wv = t >> 6, l = t & 63;
    if (wv == 0) {
        float a = (l < 49) ? alpha[l] : -1e30f;
        float m = a;
        #pragma unroll
        for (int off = 32; off; off >>= 1) m = fmaxf(m, __shfl_xor(m, off));
        float e = (l < 49) ? expf(a - m) : 0.f;
        float s = e;
        #pragma unroll
        for (int off = 32; off; off >>= 1) s += __shfl_xor(s, off);
        if (l < 49) alpha[l] = e / s;
    } else if (wv == 1) {
        float a = (l < 5) ? beta[l] : -1e30f;
        float m = a;
        #pragma unroll
        for (int off = 32; off; off >>= 1) m = fmaxf(m, __shfl_xor(m, off));
        float e = (l < 5) ? expf(a - m) : 0.f;
        float s = e;
        #pragma unroll
        for (int off = 32; off; off >>= 1) s += __shfl_xor(s, off);
        if (l < 5) beta[l] = e / s;
    }
    __syncthreads();
    const float* Vb = V + (size_t)b * 49 * 512;
    const float* Tb = T + (size_t)b * 5 * 512;
    for (int hd = t; hd < 512; hd += 256) {
        float az = 0.f;
        #pragma unroll
        for (int k = 0; k < 49; ++k) az = fmaf(alpha[k], Vb[k * 512 + hd], az);
        z_bf[(size_t)row * 512 + hd] = f2bf(az);
        float aq = 0.f;
        #pragma unroll
        for (int k = 0; k < 5; ++k) aq = fmaf(beta[k], Tb[k * 512 + hd], aq);
        q_bf[(size_t)row * 512 + hd] = f2bf(aq);
    }
}

// ---------------------------------------------------------------------------
// K4: r_t = tanh(z@Wsz.T + b_sz), s_t = tanh(q@Wsq.T + h@Wsh.T + b_sq + b_sh)
__global__ __launch_bounds__(256) void k_rs(
    const short* __restrict__ Zb, const short* __restrict__ Qb, const short* __restrict__ Hb,
    const short* __restrict__ Wsz, const short* __restrict__ Wsq, const short* __restrict__ Wsh,
    const float* __restrict__ b_sz, const float* __restrict__ b_sq, const float* __restrict__ b_sh,
    float* __restrict__ r_t, float* __restrict__ s_t)
{
    constexpr int K = 512, NN = 512;
    __shared__ __align__(16) short sA[64 * 64];
    __shared__ __align__(16) short sW[64 * 64];
    const int tid = threadIdx.x;
    const int l = tid & 63, w = tid >> 6;
    const int m0 = blockIdx.x * 64, n0 = blockIdx.y * 64;
    const int wm = (w & 1) * 32, wn = (w >> 1) * 32;
    const int lm = l & 15, lg = l >> 4;
    const int sr = l >> 3, sc = l & 7;
    f32x4 accr[2][2] = {}, accs[2][2] = {};

#define RS_PASS(AG, WG, ACC)                                                      \
    for (int k0 = 0; k0 < K; k0 += 64) {                                          \
        _Pragma("unroll")                                                         \
        for (int c = 0; c < 2; ++c) {                                             \
            const int R = w * 16 + c * 8;                                         \
            const int row = R + sr;                                               \
            GLD_LDS16((AG) + (size_t)(m0 + row) * K + k0 + ((sc ^ (row & 7)) << 3), sA + R * 64); \
            GLD_LDS16((WG) + (size_t)(n0 + row) * K + k0 + ((sc ^ (row & 7)) << 3), sW + R * 64); \
        }                                                                         \
        __syncthreads();                                                          \
        bf16x8 af[2][2], bv[2][2];                                                \
        _Pragma("unroll")                                                         \
        for (int s = 0; s < 2; ++s)                                               \
            _Pragma("unroll")                                                     \
            for (int i = 0; i < 2; ++i) {                                         \
                const int ra = wm + i * 16 + lm;                                  \
                const int rb = wn + i * 16 + lm;                                  \
                af[s][i] = *(const bf16x8*)(sA + ra * 64 + (((s * 4 + lg) ^ (ra & 7)) << 3)); \
                bv[s][i] = *(const bf16x8*)(sW + rb * 64 + (((s * 4 + lg) ^ (rb & 7)) << 3)); \
            }                                                                     \
        _Pragma("unroll")                                                         \
        for (int s = 0; s < 2; ++s)                                               \
            _Pragma("unroll")                                                     \
            for (int i = 0; i < 2; ++i)                                           \
                _Pragma("unroll")                                                 \
                for (int j = 0; j < 2; ++j)                                       \
                    ACC[i][j] = __builtin_amdgcn_mfma_f32_16x16x32_bf16(af[s][i], bv[s][j], ACC[i][j], 0, 0, 0); \
        __syncthreads();                                                          \
    }

    RS_PASS(Zb, Wsz, accr)
    RS_PASS(Qb, Wsq, accs)
    RS_PASS(Hb, Wsh, accs)
#undef RS_PASS

    #pragma unroll
    for (int j = 0; j < 2; ++j) {
        const int n = n0 + wn + j * 16 + lm;
        const float br = b_sz[n];
        const float bs = b_sq[n] + b_sh[n];
        #pragma unroll
        for (int i = 0; i < 2; ++i) {
            const int m = m0 + wm + i * 16 + lg * 4;
            #pragma unroll
            for (int q = 0; q < 4; ++q) {
                r_t[(size_t)(m + q) * NN + n] = tanhf(accr[i][j][q] + br);
                s_t[(size_t)(m + q) * NN + n] = tanhf(accs[i][j][q] + bs);
            }
        }
    }
}

// ---------------------------------------------------------------------------
// K5: MLP GEMM (round-11 proven): 128x128 tile, BK=64 single-buffered
// (32 KB LDS -> 4 blocks/CU), m97 2-barrier loop, T1 XCD swizzle, nt stores.
__global__ __launch_bounds__(256, 4) void k_gemm_mlp(
    const short* __restrict__ A, const short* __restrict__ Wb,
    const float* __restrict__ bias, float* __restrict__ C)
{
    constexpr int N = 30000, K = 512;
    __shared__ __align__(16) short shA[128 * 64];      // 16 KB
    __shared__ __align__(16) short shW[128 * 64];      // 16 KB
    const int tid = threadIdx.x;
    const int l = tid & 63, w = tid >> 6;
    const int bid = blockIdx.x;
    const int swz = (bid & 7) * 470 + (bid >> 3);      // bijective (3760%8==0)
    const int m0 = (swz & 15) * 128;                   // m fast -> W panel reuse
    const int n0 = (swz >> 4) * 128;
    const int wm = (w & 1) * 64, wn = (w >> 1) * 64;
    const int lm = l & 15, lg = l >> 4;
    const int sr = tid >> 3, sc = tid & 7;             // staging row(32/call), chunk
    const short* Ag = A  + (size_t)m0 * K;
    const short* Wg = Wb + (size_t)n0 * K;
    f32x4 acc[4][4] = {};

    for (int t = 0; t < 8; ++t) {
        const int kk = t * 64;
        #pragma unroll
        for (int c = 0; c < 4; ++c) {
            const int row = c * 32 + sr;
            GLD_LDS16(Ag + (size_t)row * K + kk + ((sc ^ (row & 7)) << 3),
                      &shA[(c * 32 + w * 8) * 64]);
            GLD_LDS16(Wg + (size_t)row * K + kk + ((sc ^ (row & 7)) << 3),
                      &shW[(c * 32 + w * 8) * 64]);
        }
        __syncthreads();                               // drains vmcnt (m97 form)
        bf16x8 af[2][4], bv[2][4];
        #pragma unroll
        for (int s = 0; s < 2; ++s)
            #pragma unroll
            for (int i = 0; i < 4; ++i) {
                const int ra = wm + i * 16 + lm;
                const int rb = wn + i * 16 + lm;
                const int ck = s * 4 + lg;
                af[s][i] = *(const bf16x8*)(&shA[ra * 64 + ((ck ^ (ra & 7)) << 3)]);
                bv[s][i] = *(const bf16x8*)(&shW[rb * 64 + ((ck ^ (rb & 7)) << 3)]);
            }
        #pragma unroll
        for (int s = 0; s < 2; ++s)
            #pragma unroll
            for (int i = 0; i < 4; ++i)
                #pragma unroll
                for (int j = 0; j < 4; ++j)
                    acc[i][j] = __builtin_amdgcn_mfma_f32_16x16x32_bf16(
                        af[s][i], bv[s][j], acc[i][j], 0, 0, 0);
        __syncthreads();                               // LDS free for next stage
    }

    // epilogue: C/D layout col = l&15, row = (l>>4)*4 + reg; nt scalar stores
    #pragma unroll
    for (int j = 0; j < 4; ++j) {
        const int n = n0 + wn + j * 16 + lm;
        if (n >= N) continue;
        const float bj = bias[n];
        #pragma unroll
        for (int i = 0; i < 4; ++i) {
            const int m = m0 + wm + i * 16 + lg * 4;
            #pragma unroll
            for (int q = 0; q < 4; ++q)
                __builtin_nontemporal_store(acc[i][j][q] + bj, &C[(size_t)(m + q) * N + n]);
        }
    }
}

// ---------------------------------------------------------------------------
// K7: fused gate + blend: each block recomputes gama for its row, then
// c_bf = bf16( g*s_t + (1-g)*r_t ).
__global__ __launch_bounds__(256) void k_blend_gate(
    const float* __restrict__ s_t, const float* __restrict__ r_t,
    const float* __restrict__ Qh,
    const float* __restrict__ W_Ss, const float* __restrict__ b_Ss,
    const float* __restrict__ W_Sr, const float* __restrict__ b_Sr,
    const float* __restrict__ W_bq, const float* __restrict__ b_bq,
    const int* __restrict__ epoch, short* __restrict__ c_bf)
{
    const int row = blockIdx.x;
    const int s = row & 127;
    const int t = threadIdx.x;
    float g = 1.0f;
    if (epoch[0] > 20) {
        const int l = t & 63;
        const int d = l * 8;
        const float4 s0 = *(const float4*)(s_t + (size_t)s * 512 + d);
        const float4 s1 = *(const float4*)(s_t + (size_t)s * 512 + d + 4);
        const float4 r0 = *(const float4*)(r_t + (size_t)s * 512 + d);
        const float4 r1 = *(const float4*)(r_t + (size_t)s * 512 + d + 4);
        float ss = b_bq[0], sr = b_bq[0];
        #pragma unroll
        for (int k = 0; k < 5; ++k) {
            const float4 w0 = *(const float4*)(W_Ss + k * 512 + d);
            const float4 w1 = *(const float4*)(W_Ss + k * 512 + d + 4);
            const float4 v0 = *(const float4*)(W_Sr + k * 512 + d);
            const float4 v1 = *(const float4*)(W_Sr + k * 512 + d + 4);
            float as = s0.x*w0.x + s0.y*w0.y + s0.z*w0.z + s0.w*w0.w
                     + s1.x*w1.x + s1.y*w1.y + s1.z*w1.z + s1.w*w1.w;
            float ar = r0.x*v0.x + r0.y*v0.y + r0.z*v0.z + r0.w*v0.w
                     + r1.x*v1.x + r1.y*v1.y + r1.z*v1.z + r1.w*v1.w;
            #pragma unroll
            for (int off = 32; off; off >>= 1) {
                as += __shfl_xor(as, off);
                ar += __shfl_xor(ar, off);
            }
            const float qh = Qh[s * 8 + k];
            ss += tanhf(as + b_Ss[k] + qh) * W_bq[k];
            sr += tanhf(ar + b_Sr[k] + qh) * W_bq[k];
        }
        g = 1.f / (1.f + expf(-(ss - sr)));
    }
    const size_t base = (size_t)row * 512;
    for (int i = t; i < 512; i += 256)
        c_bf[base + i] = f2bf(g * s_t[base + i] + (1.f - g) * r_t[base + i]);
}

// ---------------------------------------------------------------------------
extern "C" void kernel_launch(void* const* d_in, const int* in_sizes, int n_in,
                              void* d_out, int out_size, void* d_ws, size_t ws_size,
                              hipStream_t stream)
{
    const int*   epoch = (const int*)  d_in[0];
    const float* h_t   = (const float*)d_in[1];
    const float* V     = (const float*)d_in[2];
    const float* T     = (const float*)d_in[3];
    const float* W_ZV  = (const float*)d_in[4];  const float* b_ZV = (const float*)d_in[5];
    const float* W_Zh  = (const float*)d_in[6];  const float* b_Zh = (const float*)d_in[7];
    const float* W_az  = (const float*)d_in[8];  const float* b_az = (const float*)d_in[9];
    const float* W_QT  = (const float*)d_in[10]; const float* b_QT = (const float*)d_in[11];
    const float* W_Qh  = (const float*)d_in[12]; const float* b_Qh = (const float*)d_in[13];
    const float* W_bq  = (const float*)d_in[14]; const float* b_bq = (const float*)d_in[15];
    const float* W_sq  = (const float*)d_in[16]; const float* b_sq = (const float*)d_in[17];
    const float* W_sh  = (const float*)d_in[18]; const float* b_sh = (const float*)d_in[19];
    const float* W_Ss  = (const float*)d_in[20]; const float* b_Ss = (const float*)d_in[21];
    const float* W_Sr  = (const float*)d_in[22]; const float* b_Sr = (const float*)d_in[23];
    const float* W_sz  = (const float*)d_in[24]; const float* b_sz = (const float*)d_in[25];
    const float* W_mlp = (const float*)d_in[26]; const float* b_mlp= (const float*)d_in[27];

    float* out = (float*)d_out;
    float* ws  = (float*)d_ws;
    const size_t M1 = 1024 * 1024;        // 2048*512
    float* r_t  = ws;                     // 1M f
    float* s_t  = ws + M1;                // 1M f
    float* Zh   = ws + 2 * M1;            // 2048*64 f
    float* ZV   = Zh + 2048 * 64;         // 784*64 f
    float* Qh   = ZV + 784 * 64;          // 2048*8 f
    float* QT   = Qh + 2048 * 8;          // 80*8 f
    float* pad  = QT + 80 * 8;            // 128 f
    short* sreg = (short*)(pad + 128);
    short* z_bf   = sreg;                 // 1M sh
    short* q_bf   = z_bf + M1;            // 1M sh
    short* h_bf   = q_bf + M1;            // 1M sh
    short* c_bf   = h_bf + M1;            // 1M sh
    short* Wsz_bf = c_bf + M1;            // 256K sh
    short* Wsq_bf = Wsz_bf + 512 * 512;
    short* Wsh_bf = Wsq_bf + 512 * 512;
    short* V_bf   = Wsh_bf + 512 * 512;   // 832*512 sh (784 real + pad)
    short* T_bf   = V_bf + 832 * 512;     // 128*512 sh (80 real + pad)
    short* P1     = T_bf + 128 * 512;     // 64*512 sh
    short* P2     = P1 + 64 * 512;
    short* P3     = P2 + 64 * 512;
    short* W_bf   = P3 + 64 * 512;        // 30080*512 sh (incl. pad)

    k_front<<<8660, 256, 0, stream>>>(h_t, V, T, W_Zh, W_Qh, W_ZV, W_QT,
                                      P1, P2, P3, V_bf, T_bf, h_bf,
                                      W_sz, Wsz_bf, W_sq, Wsq_bf, W_sh, Wsh_bf,
                                      W_mlp, W_bf);
    k_linhv<<<47, 256, 0, stream>>>(h_bf, V_bf, T_bf, P1, P2, P3,
                                    b_Zh, b_Qh, b_ZV, b_QT, Zh, Qh, ZV, QT);
    k_attn<<<2048, 256, 0, stream>>>(V, T, ZV, Zh, QT, Qh, W_az, b_az, W_bq, b_bq, z_bf, q_bf);
    k_rs<<<dim3(32, 8), 256, 0, stream>>>(z_bf, q_bf, h_bf, Wsz_bf, Wsq_bf, Wsh_bf,
                                          b_sz, b_sq, b_sh, r_t, s_t);
    k_blend_gate<<<2048, 256, 0, stream>>>(s_t, r_t, Qh, W_Ss, b_Ss, W_Sr, b_Sr,
                                           W_bq, b_bq, epoch, c_bf);
    k_gemm_mlp<<<3760, 256, 0, stream>>>(c_bf, W_bf, b_mlp, out);
}